// Round 5
// baseline (19.050 us; speedup 1.0000x reference)
//
#include <hip/hip_runtime.h>

// PointChargeField — R5: DISAMBIGUATION PROBE (not a candidate optimization).
// R1 structure (best: 12.06 us) but the pair loop runs TWICE; second pass uses
// asm-opaqued position copies so the compiler cannot CSE the loops. Output is
// 0.5*(a1+a2) with a1==a2 bitwise -> result bit-identical to R1.
// Purpose: measure the kernel-time fraction of dur_us.
//   overhead-floor model  -> ~15.5-17 us  (+1x compute ~3.2 us)
//   GPU-bound model       -> ~24-26 us    (2x of 12.7)

#define B_ 8
#define N_ 2048
#define M_ 1024

__global__ __launch_bounds__(256) void pcf_kernel(
    const float* __restrict__ positions,        // [B,N,3]
    const float* __restrict__ charges,          // [B,M]
    const float* __restrict__ charge_positions, // [B,M,3]
    float* __restrict__ out)                    // [B,N,3]
{
    __shared__ float4 pack[M_];       // (cx,cy,cz,q) per charge: 16 KB
    __shared__ float  red[32][100];   // 32 chunks x (32 n * 3 c), padded

    const int tid = threadIdx.x;
    const int blk = blockIdx.x;
    const int b      = blk >> 6;
    const int n_base = (blk & 63) << 5;

    const float* cp = charge_positions + (size_t)b * M_ * 3;
    const float* qp = charges          + (size_t)b * M_;

    #pragma unroll
    for (int j = 0; j < 4; ++j) {
        int m = tid + 256 * j;
        pack[m] = make_float4(cp[3*m], cp[3*m+1], cp[3*m+2], qp[m]);
    }
    __syncthreads();

    const int n4    = tid & 7;
    const int chunk = tid >> 3;

    float px[4], py[4], pz[4];
    #pragma unroll
    for (int k = 0; k < 4; ++k) {
        int n = n_base + n4 + 8 * k;
        const float* p = positions + ((size_t)b * N_ + n) * 3;
        px[k] = p[0]; py[k] = p[1]; pz[k] = p[2];
    }

    // Opaque copies for pass 2 (defeats loop CSE; values identical).
    float qx[4], qy[4], qz[4];
    #pragma unroll
    for (int k = 0; k < 4; ++k) {
        qx[k] = px[k]; qy[k] = py[k]; qz[k] = pz[k];
        asm volatile("" : "+v"(qx[k]), "+v"(qy[k]), "+v"(qz[k]));
    }

    float ax[4] = {0,0,0,0}, ay[4] = {0,0,0,0}, az[4] = {0,0,0,0};
    float bx[4] = {0,0,0,0}, by[4] = {0,0,0,0}, bz[4] = {0,0,0,0};

    // Pass 1
    #pragma unroll 4
    for (int i = 0; i < 32; ++i) {
        float4 c = pack[chunk + (i << 5)];
        #pragma unroll
        for (int k = 0; k < 4; ++k) {
            float dx = px[k] - c.x;
            float dy = py[k] - c.y;
            float dz = pz[k] - c.z;
            float r2 = fmaf(dx, dx, fmaf(dy, dy, dz * dz));
            float ir  = __builtin_amdgcn_rsqf(r2);
            float ir2 = ir * ir;
            float s   = c.w * ir * ir2;
            ax[k] = fmaf(s, dx, ax[k]);
            ay[k] = fmaf(s, dy, ay[k]);
            az[k] = fmaf(s, dz, az[k]);
        }
    }

    // Pass 2 (identical math on opaque copies)
    #pragma unroll 4
    for (int i = 0; i < 32; ++i) {
        float4 c = pack[chunk + (i << 5)];
        #pragma unroll
        for (int k = 0; k < 4; ++k) {
            float dx = qx[k] - c.x;
            float dy = qy[k] - c.y;
            float dz = qz[k] - c.z;
            float r2 = fmaf(dx, dx, fmaf(dy, dy, dz * dz));
            float ir  = __builtin_amdgcn_rsqf(r2);
            float ir2 = ir * ir;
            float s   = c.w * ir * ir2;
            bx[k] = fmaf(s, dx, bx[k]);
            by[k] = fmaf(s, dy, by[k]);
            bz[k] = fmaf(s, dz, bz[k]);
        }
    }

    #pragma unroll
    for (int k = 0; k < 4; ++k) {
        int nl = n4 + 8 * k;
        red[chunk][nl * 3 + 0] = 0.5f * (ax[k] + bx[k]);
        red[chunk][nl * 3 + 1] = 0.5f * (ay[k] + by[k]);
        red[chunk][nl * 3 + 2] = 0.5f * (az[k] + bz[k]);
    }
    __syncthreads();

    if (tid < 96) {
        float s = 0.f;
        #pragma unroll
        for (int ch = 0; ch < 32; ++ch) s += red[ch][tid];
        out[((size_t)b * N_ + n_base) * 3 + tid] = s;
    }
}

extern "C" void kernel_launch(void* const* d_in, const int* in_sizes, int n_in,
                              void* d_out, int out_size, void* d_ws, size_t ws_size,
                              hipStream_t stream) {
    const float* positions        = (const float*)d_in[0];
    const float* charges          = (const float*)d_in[1];
    const float* charge_positions = (const float*)d_in[2];
    float* out = (float*)d_out;

    dim3 grid(B_ * (N_ / 32));   // 512 blocks
    dim3 block(256);
    pcf_kernel<<<grid, block, 0, stream>>>(positions, charges, charge_positions, out);
}

// Round 6
// 13.106 us; speedup vs baseline: 1.4535x; 1.4535x over previous
//
#include <hip/hip_runtime.h>

// PointChargeField: out[b,n,:] = sum_m q[b,m] * (p[b,n,:]-c[b,m,:]) / |p-c|^3
// B=8, N=2048, M=1024, all fp32.
// R6: occupancy test at constant LDS amortization. n-tile T=16, A=4 n/thread,
// C=64 chunks, 256-thr blocks, grid 1024 = 4 blocks/CU = 4 waves/SIMD
// (R1 was 2). LDS pipe stays 1.28 us/CU (A=4). Vectorized float4 staging.
// Measured decomposition (R5 probe): overhead ~6 us + kernel ~6.3 us;
// issue floor ~3.6 us -> testing whether the 1.8x gap is occupancy stalls.

#define B_ 8
#define N_ 2048
#define M_ 1024

__global__ __launch_bounds__(256) void pcf_kernel(
    const float* __restrict__ positions,        // [B,N,3]
    const float* __restrict__ charges,          // [B,M]
    const float* __restrict__ charge_positions, // [B,M,3]
    float* __restrict__ out)                    // [B,N,3]
{
    __shared__ float4 pack[M_];       // (cx,cy,cz,q): 16 KB
    __shared__ float  red[64][49];    // 64 chunks x (16 n * 3 c), pad: 12.5 KB

    const int tid = threadIdx.x;
    const int blk = blockIdx.x;
    const int b      = blk >> 7;           // 128 n-tiles per batch
    const int n_base = (blk & 127) << 4;   // tile covers 16 n-points

    const float* cp = charge_positions + (size_t)b * M_ * 3;
    const float* qp = charges          + (size_t)b * M_;

    // Vectorized staging: thread t packs charges 4t..4t+3 (3+1 float4 loads).
    {
        const float4* cp4 = (const float4*)cp;     // 768 float4
        float4 r0 = cp4[3 * tid + 0];              // x0 y0 z0 x1
        float4 r1 = cp4[3 * tid + 1];              // y1 z1 x2 y2
        float4 r2 = cp4[3 * tid + 2];              // z2 x3 y3 z3
        float4 qv = ((const float4*)qp)[tid];      // q0 q1 q2 q3
        pack[4 * tid + 0] = make_float4(r0.x, r0.y, r0.z, qv.x);
        pack[4 * tid + 1] = make_float4(r0.w, r1.x, r1.y, qv.y);
        pack[4 * tid + 2] = make_float4(r1.z, r1.w, r2.x, qv.z);
        pack[4 * tid + 3] = make_float4(r2.y, r2.z, r2.w, qv.w);
    }
    __syncthreads();

    const int n4    = tid & 3;    // 4 n-lanes
    const int chunk = tid >> 2;   // 0..63: m-chunk

    // This thread's 4 n-points (stride 4 within the 16-n tile).
    float px[4], py[4], pz[4];
    #pragma unroll
    for (int k = 0; k < 4; ++k) {
        int n = n_base + n4 + 4 * k;
        const float* p = positions + ((size_t)b * N_ + n) * 3;
        px[k] = p[0]; py[k] = p[1]; pz[k] = p[2];
    }

    float ax[4] = {0,0,0,0}, ay[4] = {0,0,0,0}, az[4] = {0,0,0,0};

    // m = chunk + 64*i, fully unrolled: ds_read_b128 imm offset 1024*i.
    // 16 distinct addrs/wave, worst 2-way alias -> free (m136).
    #pragma unroll
    for (int i = 0; i < 16; ++i) {
        float4 c = pack[chunk + (i << 6)];
        #pragma unroll
        for (int k = 0; k < 4; ++k) {
            float dx = px[k] - c.x;
            float dy = py[k] - c.y;
            float dz = pz[k] - c.z;
            float r2 = fmaf(dx, dx, fmaf(dy, dy, dz * dz));
            float ir  = __builtin_amdgcn_rsqf(r2);   // v_rsq_f32
            float ir2 = ir * ir;
            float s   = c.w * ir * ir2;              // q / r^3
            ax[k] = fmaf(s, dx, ax[k]);
            ay[k] = fmaf(s, dy, ay[k]);
            az[k] = fmaf(s, dz, az[k]);
        }
    }

    // Cross-chunk reduction in LDS.
    #pragma unroll
    for (int k = 0; k < 4; ++k) {
        int nl = n4 + 4 * k;
        red[chunk][nl * 3 + 0] = ax[k];
        red[chunk][nl * 3 + 1] = ay[k];
        red[chunk][nl * 3 + 2] = az[k];
    }
    __syncthreads();

    if (tid < 48) {
        float s = 0.f;
        #pragma unroll 8
        for (int ch = 0; ch < 64; ++ch) s += red[ch][tid];
        out[((size_t)b * N_ + n_base) * 3 + tid] = s;
    }
}

extern "C" void kernel_launch(void* const* d_in, const int* in_sizes, int n_in,
                              void* d_out, int out_size, void* d_ws, size_t ws_size,
                              hipStream_t stream) {
    const float* positions        = (const float*)d_in[0];  // [8,2048,3]
    const float* charges          = (const float*)d_in[1];  // [8,1024]
    const float* charge_positions = (const float*)d_in[2];  // [8,1024,3]
    float* out = (float*)d_out;                             // [8,2048,3]

    dim3 grid(B_ * (N_ / 16));   // 1024 blocks = 4 blocks/CU
    dim3 block(256);
    pcf_kernel<<<grid, block, 0, stream>>>(positions, charges, charge_positions, out);
}

// Round 7
// 11.975 us; speedup vs baseline: 1.5908x; 1.0944x over previous
//
#include <hip/hip_runtime.h>

// PointChargeField: out[b,n,:] = sum_m q[b,m] * (p[b,n,:]-c[b,m,:]) / |p-c|^3
// B=8, N=2048, M=1024, all fp32.
// R7: packed-FP32 inner loop. R1 tiling (best: 12.06 us; 256 thr, 32-n tile,
// thread = 4 n x 32 m, grid 512) but the 4 n-points are processed as two
// <2 x float> packs so LLVM emits v_pk_{add,mul,fma}_f32 (2 FP32/lane/instr).
// Scalar VALU 26/2pairs -> 12 packed + 2 v_rsq (no packed transcendental).
// R5 probe decomposition: ~6 us harness floor + ~6.3 us kernel (VALU-bound).

#define B_ 8
#define N_ 2048
#define M_ 1024

typedef float v2f __attribute__((ext_vector_type(2)));

__global__ __launch_bounds__(256) void pcf_kernel(
    const float* __restrict__ positions,        // [B,N,3]
    const float* __restrict__ charges,          // [B,M]
    const float* __restrict__ charge_positions, // [B,M,3]
    float* __restrict__ out)                    // [B,N,3]
{
    __shared__ float4 pack[M_];       // (cx,cy,cz,q) per charge: 16 KB
    __shared__ float  red[32][100];   // 32 chunks x (32 n * 3 c), padded

    const int tid = threadIdx.x;
    const int blk = blockIdx.x;
    const int b      = blk >> 6;          // 64 n-tiles per batch
    const int n_base = (blk & 63) << 5;   // tile covers 32 n-points

    const float* cp = charge_positions + (size_t)b * M_ * 3;
    const float* qp = charges          + (size_t)b * M_;

    // Stage packed charge data into LDS (inputs are L2-resident).
    #pragma unroll
    for (int j = 0; j < 4; ++j) {
        int m = tid + 256 * j;
        pack[m] = make_float4(cp[3*m], cp[3*m+1], cp[3*m+2], qp[m]);
    }
    __syncthreads();

    const int n4    = tid & 7;    // which of 8 n-lanes
    const int chunk = tid >> 3;   // 0..31: which 32-m chunk

    // This thread's 4 n-points, paired for packed math: (n0,n1), (n2,n3).
    float pxs[4], pys[4], pzs[4];
    #pragma unroll
    for (int k = 0; k < 4; ++k) {
        int n = n_base + n4 + 8 * k;
        const float* p = positions + ((size_t)b * N_ + n) * 3;
        pxs[k] = p[0]; pys[k] = p[1]; pzs[k] = p[2];
    }
    v2f px[2] = { {pxs[0], pxs[1]}, {pxs[2], pxs[3]} };
    v2f py[2] = { {pys[0], pys[1]}, {pys[2], pys[3]} };
    v2f pz[2] = { {pzs[0], pzs[1]}, {pzs[2], pzs[3]} };

    v2f ax[2] = { {0,0}, {0,0} };
    v2f ay[2] = { {0,0}, {0,0} };
    v2f az[2] = { {0,0}, {0,0} };

    // m = chunk + 32*i: 8 distinct b128 addrs/wave -> conflict-free broadcast.
    #pragma unroll 4
    for (int i = 0; i < 32; ++i) {
        float4 c = pack[chunk + (i << 5)];
        #pragma unroll
        for (int j = 0; j < 2; ++j) {
            v2f dx = px[j] - c.x;          // v_pk_add_f32 (neg)
            v2f dy = py[j] - c.y;
            v2f dz = pz[j] - c.z;
            v2f r2 = __builtin_elementwise_fma(dx, dx,
                     __builtin_elementwise_fma(dy, dy, dz * dz));
            v2f ir;
            ir.x = __builtin_amdgcn_rsqf(r2.x);   // v_rsq_f32 (scalar pipe)
            ir.y = __builtin_amdgcn_rsqf(r2.y);
            v2f ir2 = ir * ir;                    // v_pk_mul_f32
            v2f s   = (ir * ir2) * c.w;           // q / r^3
            ax[j] = __builtin_elementwise_fma(s, dx, ax[j]);
            ay[j] = __builtin_elementwise_fma(s, dy, ay[j]);
            az[j] = __builtin_elementwise_fma(s, dz, az[j]);
        }
    }

    // Cross-chunk reduction in LDS.
    #pragma unroll
    for (int j = 0; j < 2; ++j) {
        #pragma unroll
        for (int h = 0; h < 2; ++h) {
            int nl = n4 + 8 * (2 * j + h);
            red[chunk][nl * 3 + 0] = ax[j][h];
            red[chunk][nl * 3 + 1] = ay[j][h];
            red[chunk][nl * 3 + 2] = az[j][h];
        }
    }
    __syncthreads();

    if (tid < 96) {
        float s = 0.f;
        #pragma unroll
        for (int ch = 0; ch < 32; ++ch) s += red[ch][tid];
        out[((size_t)b * N_ + n_base) * 3 + tid] = s;
    }
}

extern "C" void kernel_launch(void* const* d_in, const int* in_sizes, int n_in,
                              void* d_out, int out_size, void* d_ws, size_t ws_size,
                              hipStream_t stream) {
    const float* positions        = (const float*)d_in[0];  // [8,2048,3]
    const float* charges          = (const float*)d_in[1];  // [8,1024]
    const float* charge_positions = (const float*)d_in[2];  // [8,1024,3]
    float* out = (float*)d_out;                             // [8,2048,3]

    dim3 grid(B_ * (N_ / 32));   // 512 blocks = 2 blocks/CU
    dim3 block(256);
    pcf_kernel<<<grid, block, 0, stream>>>(positions, charges, charge_positions, out);
}